// Round 9
// baseline (224.969 us; speedup 1.0000x reference)
//
#include <hip/hip_runtime.h>
#include <hip/hip_fp16.h>

#define N_NODES   50000
#define N_EDGES   800000
#define DF        64          // feature dim (D_IN == D_HID == 64)
#define N_GRAPHS  64
#define NPAD      50176       // 98*512, padded node count

// ---- two-level counting-sort CSR build (no global atomics, no write amp) ----
#define ABLK 200              // binning blocks
#define AEDG (N_EDGES/ABLK)   // 4000 edges per block
#define RSH  9                // 512 nodes per region
#define NREG 98               // 98*512 = 50176 >= N_NODES
#define RPAD 128              // padded region count
#define CAP  12288            // LDS image capacity per region (avg 8163)

struct H4 { __half2 a, b; };                  // 8 bytes
struct __align__(16) H8 { __half2 a, b, c, d; };  // 16 bytes (quarter row)

// Pass A1: per-block region histogram -> H transposed [region][block]
// Block 0 also zeroes the pool buffer.
__global__ __launch_bounds__(256)
void k_hist(const int* __restrict__ col, int* __restrict__ H,
            float* __restrict__ pool) {
    __shared__ int h[RPAD];
    const int t = threadIdx.x, b = blockIdx.x;
    if (b == 0)
        for (int i = t; i < N_GRAPHS * DF; i += 256) pool[i] = 0.f;
    if (t < RPAD) h[t] = 0;
    __syncthreads();
    const int e0 = b * AEDG;
    for (int i = t; i < AEDG; i += 256)
        atomicAdd(&h[col[e0 + i] >> RSH], 1);
    __syncthreads();
    if (t < RPAD) H[t * ABLK + b] = h[t];
}

// Pass A2: one block PER REGION: exclusive scan of H[r][0..199] -> O, total -> T
__global__ __launch_bounds__(256)
void k_scanH(const int* __restrict__ H, int* __restrict__ O,
             int* __restrict__ T) {
    __shared__ int s[256];
    const int t = threadIdx.x, r = blockIdx.x;
    int v = (t < ABLK) ? H[r * ABLK + t] : 0;
    s[t] = v; __syncthreads();
    #pragma unroll
    for (int off = 1; off < 256; off <<= 1) {
        int x = (t >= off) ? s[t - off] : 0;
        __syncthreads();
        s[t] += x;
        __syncthreads();
    }
    if (t < ABLK) O[r * ABLK + t] = s[t] - v;   // exclusive, region-local
    if (t == 255) T[r] = s[255];
}

// Pass A3: scatter packed edges into region-sorted staging (block-local runs).
__global__ __launch_bounds__(256)
void k_bin(const int* __restrict__ row, const int* __restrict__ col,
           const int* __restrict__ O, const int* __restrict__ T,
           unsigned* __restrict__ staging) {
    __shared__ int cur[RPAD];
    __shared__ int rs[RPAD];
    const int t = threadIdx.x, b = blockIdx.x;
    int v = 0;
    if (t < RPAD) { v = T[t]; rs[t] = v; }
    __syncthreads();
    #pragma unroll
    for (int off = 1; off < RPAD; off <<= 1) {
        int x = 0;
        if (t < RPAD && t >= off) x = rs[t - off];
        __syncthreads();
        if (t < RPAD) rs[t] += x;
        __syncthreads();
    }
    if (t < RPAD) cur[t] = O[t * ABLK + b] + (rs[t] - v);   // + R[t]
    __syncthreads();
    const int e0 = b * AEDG;
    for (int i = t; i < AEDG; i += 256) {
        int c = col[e0 + i];
        int rr = row[e0 + i];
        int slot = atomicAdd(&cur[c >> RSH], 1);      // LDS atomic
        staging[slot] = ((unsigned)c << 16) | (unsigned)rr;
    }
}

// Pass B: one block per region -> offs, dinv, epack (all coalesced writes).
// epack[e] low 16 bits = source node id (N_NODES < 65536).
__global__ __launch_bounds__(512)
void k_csr(const unsigned* __restrict__ staging, const int* __restrict__ T,
           int* __restrict__ offs, float* __restrict__ dinv,
           unsigned* __restrict__ epack) {
    __shared__ int hist[512];
    __shared__ int cur[512];
    __shared__ unsigned img[CAP];
    __shared__ int rs[RPAD];
    __shared__ int sh_s0, sh_s1;
    const int t = threadIdx.x, r = blockIdx.x;
    int v = 0;
    if (t < RPAD) { v = T[t]; rs[t] = v; }
    __syncthreads();
    #pragma unroll
    for (int off = 1; off < RPAD; off <<= 1) {
        int x = 0;
        if (t < RPAD && t >= off) x = rs[t - off];
        __syncthreads();
        if (t < RPAD) rs[t] += x;
        __syncthreads();
    }
    if (t == r) { sh_s0 = rs[t] - v; sh_s1 = rs[t]; }
    hist[t] = 0;
    __syncthreads();
    const int s0 = sh_s0, s1 = sh_s1;
    for (int i = s0 + t; i < s1; i += 512) {
        int ln = (int)(staging[i] >> 16) - (r << RSH);
        atomicAdd(&hist[ln], 1);
    }
    __syncthreads();
    int myc = hist[t];
    #pragma unroll
    for (int off = 1; off < 512; off <<= 1) {         // inclusive scan
        int x = (t >= off) ? hist[t - off] : 0;
        __syncthreads();
        hist[t] += x;
        __syncthreads();
    }
    int excl = hist[t] - myc;
    int n = (r << RSH) + t;
    offs[n] = s0 + excl;                               // incl. sentinel nodes
    if (n < N_NODES) dinv[n] = rsqrtf((float)(myc + 1));
    cur[t] = excl;
    __syncthreads();
    for (int i = s0 + t; i < s1; i += 512) {
        unsigned p = staging[i];
        int ln = (int)(p >> 16) - (r << RSH);
        unsigned rr = p & 0xFFFFu;
        unsigned pk = rr | ((unsigned)ln << 16);
        int slot = atomicAdd(&cur[ln], 1);             // LDS atomic
        if (slot < CAP) img[slot] = pk;
        else           epack[s0 + slot] = pk;          // overflow fallback
    }
    __syncthreads();
    int cnt = s1 - s0; if (cnt > CAP) cnt = CAP;
    for (int j = t; j < cnt; j += 512) epack[s0 + j] = img[j];
}

// ---- k_scale: hs = fp16( dinv (.) x )  (row-wise prescale for layer 1) ----
__global__ __launch_bounds__(256)
void k_scale(const float* __restrict__ x, const float* __restrict__ dinv,
             __half* __restrict__ hs) {
    int i = blockIdx.x * blockDim.x + threadIdx.x;     // 4-elem index
    if (i < N_NODES * DF / 4) {
        int n = (i * 4) >> 6;
        float s = dinv[n];
        float4 v = ((const float4*)x)[i];
        H4 h;
        h.a = __floats2half2_rn(v.x * s, v.y * s);
        h.b = __floats2half2_rn(v.z * s, v.w * s);
        ((H4*)hs)[i] = h;
    }
}

// ---------------- fused gather + GEMM (+ pool epilogue), R9 structure --------
// R9 = R8 with gather reorganized 4x16x2sets -> 8x8x1set: each wave runs its
// 8 nodes CONCURRENTLY (8 lanes per node, 16 B H8 quarter-row per lane; a
// group's 8 lanes still fetch exactly one 128-B line per edge). 64 independent
// row loads in flight per wave (was 32) and no sequential set bubble. Same
// line count, same wave-wide VALU per edge. (512,6): grid gives 3.05
// blocks/CU anyway; VGPR budget ~85 avoids R6's squeeze.
#define FB_ROWS 64
#define LDX 68
#define ECAP 2048            // staged edges per block (avg span ~1030, ~16 sigma)

__global__ __launch_bounds__(512, 6)
void k_fused(const int* __restrict__ offs, const unsigned* __restrict__ epack,
             const float* __restrict__ dinv, const __half* __restrict__ hs,
             const float* __restrict__ W, const float* __restrict__ bias,
             __half* __restrict__ out, const int* __restrict__ batch,
             float* __restrict__ pool) {
    __shared__ float  XsT[DF][LDX];        // 17.4 KB, transposed agg tile
    __shared__ float  Ws[DF][DF];          // 16 KB
    __shared__ unsigned short es_l[ECAP];  // 4 KB: src ids
    __shared__ int    s_offs[FB_ROWS + 1];
    __shared__ float  plocal[4 * DF];      // block-local pool partials
    __shared__ int    sh_batch[FB_ROWS];

    const int t = threadIdx.x;
    const int row0 = blockIdx.x * FB_ROWS;

    // ---- phase 0: stage W, offs slice; (layer 3) pool meta ----
    for (int idx = t * 4; idx < DF * DF; idx += 512 * 4) {
        float4 w = *(const float4*)&W[idx];
        Ws[idx >> 6][(idx & 63) + 0] = w.x;
        Ws[idx >> 6][(idx & 63) + 1] = w.y;
        Ws[idx >> 6][(idx & 63) + 2] = w.z;
        Ws[idx >> 6][(idx & 63) + 3] = w.w;
    }
    if (t <= FB_ROWS) s_offs[t] = offs[row0 + t];
    if (pool) {
        if (t < 4 * DF) plocal[t] = 0.f;
        if (t < FB_ROWS) {
            int n = row0 + t;
            sh_batch[t] = batch[n < N_NODES ? n : N_NODES - 1];
        }
    }
    __syncthreads();

    // ---- phase A: stage src ids for the block's edge span (fast path) ----
    const int eb  = s_offs[0];
    const int cnt = s_offs[FB_ROWS] - eb;
    if (cnt <= ECAP)
        for (int i = t; i < cnt; i += 512)
            es_l[i] = (unsigned short)(epack[eb + i] & 0xFFFFu);
    __syncthreads();

    // ---- phase 1: gather. wave = 8 node-groups x 8 feature lanes, 1 set ----
    const int wv = t >> 6;
    const int l  = t & 63;
    const int g8 = l >> 3;          // node sub-group 0..7
    const int o8 = (l & 7) << 3;    // feature offset 0..56 (8 features/lane)

    {
        const int r = (wv << 3) + g8;              // node row in tile 0..63
        const int n = row0 + r;
        const float dc = (n < N_NODES) ? dinv[n] : 0.f;
        const unsigned hn = (n < N_NODES) ? (unsigned)n : 0u;

        // self-loop seed: hs[n] (= dinv*h); final write scales by dc -> dc^2*h
        float acc[8];
        {
            H8 sv = *(const H8*)&hs[(hn << 6) + o8];
            float2 f0 = __half22float2(sv.a), f1 = __half22float2(sv.b);
            float2 f2 = __half22float2(sv.c), f3 = __half22float2(sv.d);
            acc[0] = f0.x; acc[1] = f0.y; acc[2] = f1.x; acc[3] = f1.y;
            acc[4] = f2.x; acc[5] = f2.y; acc[6] = f3.x; acc[7] = f3.y;
        }

        int s        = s_offs[r]     - eb;
        const int s1 = s_offs[r + 1] - eb;
        if (cnt <= ECAP) {
            while (s < s1) {                   // divergent across groups: ok
                unsigned srcs[8];
                #pragma unroll
                for (int k = 0; k < 8; ++k) {
                    const int li = s + k;
                    srcs[k] = (li < s1) ? (unsigned)es_l[li] : hn;
                }
                H8 v[8];
                #pragma unroll
                for (int k = 0; k < 8; ++k)
                    v[k] = *(const H8*)&hs[(srcs[k] << 6) + o8];
                #pragma unroll
                for (int k = 0; k < 8; ++k) {
                    const float m = (s + k < s1) ? 1.f : 0.f;
                    float2 f0 = __half22float2(v[k].a);
                    float2 f1 = __half22float2(v[k].b);
                    float2 f2 = __half22float2(v[k].c);
                    float2 f3 = __half22float2(v[k].d);
                    acc[0] += m * f0.x; acc[1] += m * f0.y;
                    acc[2] += m * f1.x; acc[3] += m * f1.y;
                    acc[4] += m * f2.x; acc[5] += m * f2.y;
                    acc[6] += m * f3.x; acc[7] += m * f3.y;
                }
                s += 8;
            }
        } else {
            // block-uniform slow path (span > ECAP: ~never)
            while (s < s1) {
                unsigned srcs[8];
                #pragma unroll
                for (int k = 0; k < 8; ++k) {
                    const int li = s + k;
                    srcs[k] = (li < s1) ? (epack[eb + li] & 0xFFFFu) : hn;
                }
                H8 v[8];
                #pragma unroll
                for (int k = 0; k < 8; ++k)
                    v[k] = *(const H8*)&hs[(srcs[k] << 6) + o8];
                #pragma unroll
                for (int k = 0; k < 8; ++k) {
                    const float m = (s + k < s1) ? 1.f : 0.f;
                    float2 f0 = __half22float2(v[k].a);
                    float2 f1 = __half22float2(v[k].b);
                    float2 f2 = __half22float2(v[k].c);
                    float2 f3 = __half22float2(v[k].d);
                    acc[0] += m * f0.x; acc[1] += m * f0.y;
                    acc[2] += m * f1.x; acc[3] += m * f1.y;
                    acc[4] += m * f2.x; acc[5] += m * f2.y;
                    acc[6] += m * f3.x; acc[7] += m * f3.y;
                }
                s += 8;
            }
        }

        #pragma unroll
        for (int f = 0; f < 8; ++f)
            XsT[o8 + f][r] = acc[f] * dc;
    }
    __syncthreads();

    // ---- phase 2: GEMM, 4x2 register tile per thread (512 thr / 4096 out) ----
    const int i = (t & 15) * 4;   // row offset in tile
    const int j = (t >> 4) * 2;   // col offset (0..62, even)
    float acc[4][2] = {};
    #pragma unroll 8
    for (int k = 0; k < DF; ++k) {
        float4 xv = *(const float4*)&XsT[k][i];
        float2 wvv = *(const float2*)&Ws[k][j];
        acc[0][0] += xv.x * wvv.x; acc[0][1] += xv.x * wvv.y;
        acc[1][0] += xv.y * wvv.x; acc[1][1] += xv.y * wvv.y;
        acc[2][0] += xv.z * wvv.x; acc[2][1] += xv.z * wvv.y;
        acc[3][0] += xv.w * wvv.x; acc[3][1] += xv.w * wvv.y;
    }
    const float bx = bias[j], by = bias[j + 1];

    if (!pool) {
        // layers 1-2: write NEXT layer's prescaled fp16 input hs = dinv*relu(o)
        #pragma unroll
        for (int u = 0; u < 4; ++u) {
            int gr = row0 + i + u;
            if (gr < N_NODES) {
                float sc = dinv[gr];
                float ox = acc[u][0] + bx;
                float oy = acc[u][1] + by;
                ox = ox > 0.f ? ox : 0.f;
                oy = oy > 0.f ? oy : 0.f;
                *(__half2*)&out[gr * DF + j] = __floats2half2_rn(ox * sc, oy * sc);
            }
        }
    } else {
        // layer-3 epilogue: relu then block-local mean-pool accumulation.
        const int g0 = sh_batch[0];
        const int span = sh_batch[FB_ROWS - 1] - g0 + 1;
        if (span <= 4) {
            #pragma unroll
            for (int u = 0; u < 4; ++u) {
                int gr = row0 + i + u;
                if (gr < N_NODES) {
                    float ox = acc[u][0] + bx;
                    float oy = acc[u][1] + by;
                    ox = ox > 0.f ? ox : 0.f;
                    oy = oy > 0.f ? oy : 0.f;
                    int gl = sh_batch[i + u] - g0;
                    atomicAdd(&plocal[gl * DF + j],     ox);
                    atomicAdd(&plocal[gl * DF + j + 1], oy);
                }
            }
            __syncthreads();
            for (int idx = t; idx < span * DF; idx += 512)
                atomicAdd(&pool[g0 * DF + idx], plocal[idx]);
        } else {
            // defensive fallback (sorted batch, ~781 nodes/graph: never hit)
            #pragma unroll
            for (int u = 0; u < 4; ++u) {
                int gr = row0 + i + u;
                if (gr < N_NODES) {
                    float ox = acc[u][0] + bx;
                    float oy = acc[u][1] + by;
                    ox = ox > 0.f ? ox : 0.f;
                    oy = oy > 0.f ? oy : 0.f;
                    int gg = sh_batch[i + u];
                    atomicAdd(&pool[gg * DF + j],     ox);
                    atomicAdd(&pool[gg * DF + j + 1], oy);
                }
            }
        }
    }
}

// ---------------- final divide; counts via binary search on sorted batch ----
__device__ __forceinline__ int lb(const int* a, int n, int key) {
    int lo = 0, hi = n;
    while (lo < hi) { int m = (lo + hi) >> 1; if (a[m] < key) lo = m + 1; else hi = m; }
    return lo;
}

__global__ void k_div(const float* __restrict__ pool, const int* __restrict__ batch,
                      float* __restrict__ out) {
    int idx = blockIdx.x * blockDim.x + threadIdx.x;
    if (idx < N_GRAPHS * DF) {
        int g = idx >> 6;
        int c = lb(batch, N_NODES, g + 1) - lb(batch, N_NODES, g);
        out[idx] = pool[idx] / fmaxf((float)c, 1.0f);
    }
}

// ---------------- launch ----------------

extern "C" void kernel_launch(void* const* d_in, const int* in_sizes, int n_in,
                              void* d_out, int out_size, void* d_ws, size_t ws_size,
                              hipStream_t stream) {
    const float* x     = (const float*)d_in[0];
    const int*   ei    = (const int*)d_in[1];      // [2, E] flat: row then col
    const int*   batch = (const int*)d_in[2];
    const float* W1    = (const float*)d_in[3];
    const float* b1    = (const float*)d_in[4];
    const float* W2    = (const float*)d_in[5];
    const float* b2    = (const float*)d_in[6];
    const float* W3    = (const float*)d_in[7];
    const float* b3    = (const float*)d_in[8];
    float* out = (float*)d_out;

    const int* row = ei;             // source
    const int* col = ei + N_EDGES;   // target (aggregation index)

    // workspace layout (4-byte elements; fp16 buffers alias the float slots)
    char* wsb = (char*)d_ws;
    float*    pool    = (float*)wsb;                     // N_GRAPHS*DF
    int*      H       = (int*)(pool + N_GRAPHS * DF);    // RPAD*ABLK (transposed)
    int*      O       = H + RPAD * ABLK;                 // RPAD*ABLK (transposed)
    int*      T       = O + RPAD * ABLK;                 // RPAD
    int*      offs    = T + RPAD;                        // NPAD
    unsigned* epack   = (unsigned*)(offs + NPAD);        // N_EDGES
    unsigned* staging = epack + N_EDGES;                 // N_EDGES
    float*    dinv    = (float*)(staging + N_EDGES);     // NPAD
    __half*   bufA    = (__half*)(dinv + NPAD);          // N_NODES*DF halves
    __half*   bufB    = (__half*)((float*)bufA + N_NODES * DF);

    const int nblk_F = (N_NODES + FB_ROWS - 1) / FB_ROWS;    // 782
    const int nblk_S = (N_NODES * DF / 4 + 255) / 256;       // 3125

    // CSR build: hist (also zeroes pool) -> per-region scan -> bin -> CSR
    k_hist<<<ABLK, 256, 0, stream>>>(col, H, pool);
    k_scanH<<<RPAD, 256, 0, stream>>>(H, O, T);
    k_bin<<<ABLK, 256, 0, stream>>>(row, col, O, T, staging);
    k_csr<<<NREG, 512, 0, stream>>>(staging, T, offs, dinv, epack);

    // layer-1 prescale: bufB = fp16(dinv (.) x)   (bufB free until layer 2)
    k_scale<<<nblk_S, 256, 0, stream>>>(x, dinv, bufB);

    // fused layers: hs_next = fp16(dinv (.) relu((A_hat-sum of hs) @ W + b))
    k_fused<<<nblk_F, 512, 0, stream>>>(offs, epack, dinv, bufB, W1, b1, bufA,
                                        nullptr, nullptr);
    k_fused<<<nblk_F, 512, 0, stream>>>(offs, epack, dinv, bufA, W2, b2, bufB,
                                        nullptr, nullptr);
    // layer 3: no h write; outputs pooled directly (pool zeroed by k_hist)
    k_fused<<<nblk_F, 512, 0, stream>>>(offs, epack, dinv, bufB, W3, b3, nullptr,
                                        batch, pool);

    k_div<<<(N_GRAPHS * DF + 255) / 256, 256, 0, stream>>>(pool, batch, out);
}

// Round 10
// 214.561 us; speedup vs baseline: 1.0485x; 1.0485x over previous
//
#include <hip/hip_runtime.h>
#include <hip/hip_fp16.h>

#define N_NODES   50000
#define N_EDGES   800000
#define DF        64          // feature dim (D_IN == D_HID == 64)
#define N_GRAPHS  64
#define NPAD      50176       // 98*512, padded node count

// ---- two-level counting-sort CSR build (no global atomics, no write amp) ----
#define ABLK 200              // binning blocks
#define AEDG (N_EDGES/ABLK)   // 4000 edges per block
#define RSH  9                // 512 nodes per region
#define NREG 98               // 98*512 = 50176 >= N_NODES
#define RPAD 128              // padded region count
#define CAP  12288            // LDS image capacity per region (avg 8163)

struct H4 { __half2 a, b; };                      // 8 bytes
struct __align__(16) H8 { __half2 a, b, c, d; };  // 16 bytes

// Pass A1: per-block region histogram -> H transposed [region][block]
// Block 0 also zeroes the pool buffer.
__global__ __launch_bounds__(256)
void k_hist(const int* __restrict__ col, int* __restrict__ H,
            float* __restrict__ pool) {
    __shared__ int h[RPAD];
    const int t = threadIdx.x, b = blockIdx.x;
    if (b == 0)
        for (int i = t; i < N_GRAPHS * DF; i += 256) pool[i] = 0.f;
    if (t < RPAD) h[t] = 0;
    __syncthreads();
    const int e0 = b * AEDG;
    for (int i = t; i < AEDG; i += 256)
        atomicAdd(&h[col[e0 + i] >> RSH], 1);
    __syncthreads();
    if (t < RPAD) H[t * ABLK + b] = h[t];
}

// Pass A2: one block PER REGION: exclusive scan of H[r][0..199] -> O, total -> T
__global__ __launch_bounds__(256)
void k_scanH(const int* __restrict__ H, int* __restrict__ O,
             int* __restrict__ T) {
    __shared__ int s[256];
    const int t = threadIdx.x, r = blockIdx.x;
    int v = (t < ABLK) ? H[r * ABLK + t] : 0;
    s[t] = v; __syncthreads();
    #pragma unroll
    for (int off = 1; off < 256; off <<= 1) {
        int x = (t >= off) ? s[t - off] : 0;
        __syncthreads();
        s[t] += x;
        __syncthreads();
    }
    if (t < ABLK) O[r * ABLK + t] = s[t] - v;   // exclusive, region-local
    if (t == 255) T[r] = s[255];
}

// Pass A3: scatter packed edges into region-sorted staging (block-local runs).
__global__ __launch_bounds__(256)
void k_bin(const int* __restrict__ row, const int* __restrict__ col,
           const int* __restrict__ O, const int* __restrict__ T,
           unsigned* __restrict__ staging) {
    __shared__ int cur[RPAD];
    __shared__ int rs[RPAD];
    const int t = threadIdx.x, b = blockIdx.x;
    int v = 0;
    if (t < RPAD) { v = T[t]; rs[t] = v; }
    __syncthreads();
    #pragma unroll
    for (int off = 1; off < RPAD; off <<= 1) {
        int x = 0;
        if (t < RPAD && t >= off) x = rs[t - off];
        __syncthreads();
        if (t < RPAD) rs[t] += x;
        __syncthreads();
    }
    if (t < RPAD) cur[t] = O[t * ABLK + b] + (rs[t] - v);   // + R[t]
    __syncthreads();
    const int e0 = b * AEDG;
    for (int i = t; i < AEDG; i += 256) {
        int c = col[e0 + i];
        int rr = row[e0 + i];
        int slot = atomicAdd(&cur[c >> RSH], 1);      // LDS atomic
        staging[slot] = ((unsigned)c << 16) | (unsigned)rr;
    }
}

// Pass B: one block per region -> offs, dinv, epack (all coalesced writes).
// epack[e] low 16 bits = source node id (N_NODES < 65536).
// R10: tail also performs the layer-1 prescale hs = fp16(dinv (.) x) for this
// region's 512 nodes (dinv is already in LDS) -> k_scale dispatch eliminated.
__global__ __launch_bounds__(512)
void k_csr(const unsigned* __restrict__ staging, const int* __restrict__ T,
           int* __restrict__ offs, float* __restrict__ dinv,
           unsigned* __restrict__ epack,
           const float* __restrict__ x, __half* __restrict__ hs) {
    __shared__ int hist[512];
    __shared__ int cur[512];
    __shared__ unsigned img[CAP];
    __shared__ int rs[RPAD];
    __shared__ float sdv[512];
    __shared__ int sh_s0, sh_s1;
    const int t = threadIdx.x, r = blockIdx.x;
    int v = 0;
    if (t < RPAD) { v = T[t]; rs[t] = v; }
    __syncthreads();
    #pragma unroll
    for (int off = 1; off < RPAD; off <<= 1) {
        int x2 = 0;
        if (t < RPAD && t >= off) x2 = rs[t - off];
        __syncthreads();
        if (t < RPAD) rs[t] += x2;
        __syncthreads();
    }
    if (t == r) { sh_s0 = rs[t] - v; sh_s1 = rs[t]; }
    hist[t] = 0;
    __syncthreads();
    const int s0 = sh_s0, s1 = sh_s1;
    for (int i = s0 + t; i < s1; i += 512) {
        int ln = (int)(staging[i] >> 16) - (r << RSH);
        atomicAdd(&hist[ln], 1);
    }
    __syncthreads();
    int myc = hist[t];
    #pragma unroll
    for (int off = 1; off < 512; off <<= 1) {         // inclusive scan
        int x2 = (t >= off) ? hist[t - off] : 0;
        __syncthreads();
        hist[t] += x2;
        __syncthreads();
    }
    int excl = hist[t] - myc;
    int n = (r << RSH) + t;
    offs[n] = s0 + excl;                               // incl. sentinel nodes
    float dv = (n < N_NODES) ? rsqrtf((float)(myc + 1)) : 0.f;
    if (n < N_NODES) dinv[n] = dv;
    sdv[t] = dv;
    cur[t] = excl;
    __syncthreads();
    for (int i = s0 + t; i < s1; i += 512) {
        unsigned p = staging[i];
        int ln = (int)(p >> 16) - (r << RSH);
        unsigned rr = p & 0xFFFFu;
        unsigned pk = rr | ((unsigned)ln << 16);
        int slot = atomicAdd(&cur[ln], 1);             // LDS atomic
        if (slot < CAP) img[slot] = pk;
        else           epack[s0 + slot] = pk;          // overflow fallback
    }
    __syncthreads();
    int cnt = s1 - s0; if (cnt > CAP) cnt = CAP;
    for (int j = t; j < cnt; j += 512) epack[s0 + j] = img[j];

    // ---- tail: layer-1 prescale for this region (fully coalesced) ----
    // 8 lanes per node x 8 features (H8); 64 nodes per pass, 8 passes.
    const int lane = t & 7;
    for (int p = 0; p < 8; ++p) {
        int nl = p * 64 + (t >> 3);                    // local node 0..511
        int n2 = (r << RSH) + nl;
        if (n2 < N_NODES) {
            float s = sdv[nl];
            const float4* xp = (const float4*)&x[n2 * DF + lane * 8];
            float4 a = xp[0], b = xp[1];
            H8 h;
            h.a = __floats2half2_rn(a.x * s, a.y * s);
            h.b = __floats2half2_rn(a.z * s, a.w * s);
            h.c = __floats2half2_rn(b.x * s, b.y * s);
            h.d = __floats2half2_rn(b.z * s, b.w * s);
            *(H8*)&hs[n2 * DF + lane * 8] = h;
        }
    }
}

// ---------------- fused gather + GEMM (+ pool epilogue), R8 structure --------
// R8 body (session best: 51.4 us/layer, VGPR 28, no spill). FP16 hidden-state
// storage: each hs row is 128 B = ONE cache line; footprint 6.4 MB. All
// arithmetic stays fp32. R4-R9 established the gather is bound by the memory
// system's random-line service rate (~37 cy/line/CU = outstanding-miss
// capacity x L2/L3 latency): concurrency levers (waves R7, chains R9) are
// falsified, byte lever exhausted at fp16 (fp8 fails accuracy by ~6x).
#define FB_ROWS 64
#define LDX 68
#define ECAP 2048            // staged edges per block (avg span ~1030, ~16 sigma)

__global__ __launch_bounds__(512, 8)
void k_fused(const int* __restrict__ offs, const unsigned* __restrict__ epack,
             const float* __restrict__ dinv, const __half* __restrict__ hs,
             const float* __restrict__ W, const float* __restrict__ bias,
             __half* __restrict__ out, const int* __restrict__ batch,
             float* __restrict__ pool) {
    __shared__ float  XsT[DF][LDX];        // 17.4 KB, transposed agg tile
    __shared__ float  Ws[DF][DF];          // 16 KB
    __shared__ unsigned short es_l[ECAP];  // 4 KB: src ids
    __shared__ int    s_offs[FB_ROWS + 1];
    __shared__ float  plocal[4 * DF];      // block-local pool partials
    __shared__ int    sh_batch[FB_ROWS];

    const int t = threadIdx.x;
    const int row0 = blockIdx.x * FB_ROWS;

    // ---- phase 0: stage W, offs slice; (layer 3) pool meta ----
    for (int idx = t * 4; idx < DF * DF; idx += 512 * 4) {
        float4 w = *(const float4*)&W[idx];
        Ws[idx >> 6][(idx & 63) + 0] = w.x;
        Ws[idx >> 6][(idx & 63) + 1] = w.y;
        Ws[idx >> 6][(idx & 63) + 2] = w.z;
        Ws[idx >> 6][(idx & 63) + 3] = w.w;
    }
    if (t <= FB_ROWS) s_offs[t] = offs[row0 + t];
    if (pool) {
        if (t < 4 * DF) plocal[t] = 0.f;
        if (t < FB_ROWS) {
            int n = row0 + t;
            sh_batch[t] = batch[n < N_NODES ? n : N_NODES - 1];
        }
    }
    __syncthreads();

    // ---- phase A: stage src ids for the block's edge span (fast path) ----
    const int eb  = s_offs[0];
    const int cnt = s_offs[FB_ROWS] - eb;
    if (cnt <= ECAP)
        for (int i = t; i < cnt; i += 512)
            es_l[i] = (unsigned short)(epack[eb + i] & 0xFFFFu);
    __syncthreads();

    // ---- phase 1: gather. wave = 4 node-groups x 16 feature lanes ----
    const int wv = t >> 6;
    const int l  = t & 63;
    const int ng = l >> 4;          // node sub-group 0..3
    const int q4 = (l & 15) << 2;   // feature offset 0..60

    for (int set = 0; set < 2; ++set) {
        const int r = (wv << 3) + (set << 2) + ng;
        const int n = row0 + r;
        const float dc = (n < N_NODES) ? dinv[n] : 0.f;
        const unsigned hn = (n < N_NODES) ? (unsigned)n : 0u;

        // self-loop seed: hs[n] (= dinv*h); final write scales by dc -> dc^2*h
        float4 acc;
        {
            H4 sv = *(const H4*)&hs[(hn << 6) + q4];
            float2 fa = __half22float2(sv.a), fb = __half22float2(sv.b);
            acc.x = fa.x; acc.y = fa.y; acc.z = fb.x; acc.w = fb.y;
        }

        int s        = s_offs[r]     - eb;
        const int s1 = s_offs[r + 1] - eb;
        if (cnt <= ECAP) {
            while (s < s1) {                       // divergent across groups: ok
                unsigned srcs[8];
                #pragma unroll
                for (int k = 0; k < 8; ++k) {
                    const int li = s + k;
                    srcs[k] = (li < s1) ? (unsigned)es_l[li] : hn;
                }
                H4 v[8];
                #pragma unroll
                for (int k = 0; k < 8; ++k)
                    v[k] = *(const H4*)&hs[(srcs[k] << 6) + q4];
                #pragma unroll
                for (int k = 0; k < 8; ++k) {
                    const float m = (s + k < s1) ? 1.f : 0.f;
                    float2 fa = __half22float2(v[k].a);
                    float2 fb = __half22float2(v[k].b);
                    acc.x += m * fa.x; acc.y += m * fa.y;
                    acc.z += m * fb.x; acc.w += m * fb.y;
                }
                s += 8;
            }
        } else {
            // block-uniform slow path (span > ECAP: ~never)
            while (s < s1) {
                unsigned srcs[8];
                #pragma unroll
                for (int k = 0; k < 8; ++k) {
                    const int li = s + k;
                    srcs[k] = (li < s1) ? (epack[eb + li] & 0xFFFFu) : hn;
                }
                H4 v[8];
                #pragma unroll
                for (int k = 0; k < 8; ++k)
                    v[k] = *(const H4*)&hs[(srcs[k] << 6) + q4];
                #pragma unroll
                for (int k = 0; k < 8; ++k) {
                    const float m = (s + k < s1) ? 1.f : 0.f;
                    float2 fa = __half22float2(v[k].a);
                    float2 fb = __half22float2(v[k].b);
                    acc.x += m * fa.x; acc.y += m * fa.y;
                    acc.z += m * fb.x; acc.w += m * fb.y;
                }
                s += 8;
            }
        }

        XsT[q4 + 0][r] = acc.x * dc;
        XsT[q4 + 1][r] = acc.y * dc;
        XsT[q4 + 2][r] = acc.z * dc;
        XsT[q4 + 3][r] = acc.w * dc;
    }
    __syncthreads();

    // ---- phase 2: GEMM, 4x2 register tile per thread (512 thr / 4096 out) ----
    const int i = (t & 15) * 4;   // row offset in tile
    const int j = (t >> 4) * 2;   // col offset (0..62, even)
    float acc[4][2] = {};
    #pragma unroll 8
    for (int k = 0; k < DF; ++k) {
        float4 xv = *(const float4*)&XsT[k][i];
        float2 wvv = *(const float2*)&Ws[k][j];
        acc[0][0] += xv.x * wvv.x; acc[0][1] += xv.x * wvv.y;
        acc[1][0] += xv.y * wvv.x; acc[1][1] += xv.y * wvv.y;
        acc[2][0] += xv.z * wvv.x; acc[2][1] += xv.z * wvv.y;
        acc[3][0] += xv.w * wvv.x; acc[3][1] += xv.w * wvv.y;
    }
    const float bx = bias[j], by = bias[j + 1];

    if (!pool) {
        // layers 1-2: write NEXT layer's prescaled fp16 input hs = dinv*relu(o)
        #pragma unroll
        for (int u = 0; u < 4; ++u) {
            int gr = row0 + i + u;
            if (gr < N_NODES) {
                float sc = dinv[gr];
                float ox = acc[u][0] + bx;
                float oy = acc[u][1] + by;
                ox = ox > 0.f ? ox : 0.f;
                oy = oy > 0.f ? oy : 0.f;
                *(__half2*)&out[gr * DF + j] = __floats2half2_rn(ox * sc, oy * sc);
            }
        }
    } else {
        // layer-3 epilogue: relu then block-local mean-pool accumulation.
        const int g0 = sh_batch[0];
        const int span = sh_batch[FB_ROWS - 1] - g0 + 1;
        if (span <= 4) {
            #pragma unroll
            for (int u = 0; u < 4; ++u) {
                int gr = row0 + i + u;
                if (gr < N_NODES) {
                    float ox = acc[u][0] + bx;
                    float oy = acc[u][1] + by;
                    ox = ox > 0.f ? ox : 0.f;
                    oy = oy > 0.f ? oy : 0.f;
                    int gl = sh_batch[i + u] - g0;
                    atomicAdd(&plocal[gl * DF + j],     ox);
                    atomicAdd(&plocal[gl * DF + j + 1], oy);
                }
            }
            __syncthreads();
            for (int idx = t; idx < span * DF; idx += 512)
                atomicAdd(&pool[g0 * DF + idx], plocal[idx]);
        } else {
            // defensive fallback (sorted batch, ~781 nodes/graph: never hit)
            #pragma unroll
            for (int u = 0; u < 4; ++u) {
                int gr = row0 + i + u;
                if (gr < N_NODES) {
                    float ox = acc[u][0] + bx;
                    float oy = acc[u][1] + by;
                    ox = ox > 0.f ? ox : 0.f;
                    oy = oy > 0.f ? oy : 0.f;
                    int gg = sh_batch[i + u];
                    atomicAdd(&pool[gg * DF + j],     ox);
                    atomicAdd(&pool[gg * DF + j + 1], oy);
                }
            }
        }
    }
}

// ---------------- final divide; counts via binary search on sorted batch ----
__device__ __forceinline__ int lb(const int* a, int n, int key) {
    int lo = 0, hi = n;
    while (lo < hi) { int m = (lo + hi) >> 1; if (a[m] < key) lo = m + 1; else hi = m; }
    return lo;
}

__global__ void k_div(const float* __restrict__ pool, const int* __restrict__ batch,
                      float* __restrict__ out) {
    int idx = blockIdx.x * blockDim.x + threadIdx.x;
    if (idx < N_GRAPHS * DF) {
        int g = idx >> 6;
        int c = lb(batch, N_NODES, g + 1) - lb(batch, N_NODES, g);
        out[idx] = pool[idx] / fmaxf((float)c, 1.0f);
    }
}

// ---------------- launch ----------------

extern "C" void kernel_launch(void* const* d_in, const int* in_sizes, int n_in,
                              void* d_out, int out_size, void* d_ws, size_t ws_size,
                              hipStream_t stream) {
    const float* x     = (const float*)d_in[0];
    const int*   ei    = (const int*)d_in[1];      // [2, E] flat: row then col
    const int*   batch = (const int*)d_in[2];
    const float* W1    = (const float*)d_in[3];
    const float* b1    = (const float*)d_in[4];
    const float* W2    = (const float*)d_in[5];
    const float* b2    = (const float*)d_in[6];
    const float* W3    = (const float*)d_in[7];
    const float* b3    = (const float*)d_in[8];
    float* out = (float*)d_out;

    const int* row = ei;             // source
    const int* col = ei + N_EDGES;   // target (aggregation index)

    // workspace layout (4-byte elements; fp16 buffers alias the float slots)
    char* wsb = (char*)d_ws;
    float*    pool    = (float*)wsb;                     // N_GRAPHS*DF
    int*      H       = (int*)(pool + N_GRAPHS * DF);    // RPAD*ABLK (transposed)
    int*      O       = H + RPAD * ABLK;                 // RPAD*ABLK (transposed)
    int*      T       = O + RPAD * ABLK;                 // RPAD
    int*      offs    = T + RPAD;                        // NPAD
    unsigned* epack   = (unsigned*)(offs + NPAD);        // N_EDGES
    unsigned* staging = epack + N_EDGES;                 // N_EDGES
    float*    dinv    = (float*)(staging + N_EDGES);     // NPAD
    __half*   bufA    = (__half*)(dinv + NPAD);          // N_NODES*DF halves
    __half*   bufB    = (__half*)((float*)bufA + N_NODES * DF);

    const int nblk_F = (N_NODES + FB_ROWS - 1) / FB_ROWS;    // 782

    // CSR build: hist (also zeroes pool) -> per-region scan -> bin -> CSR
    // k_csr tail also writes the layer-1 prescaled fp16 input into bufB.
    k_hist<<<ABLK, 256, 0, stream>>>(col, H, pool);
    k_scanH<<<RPAD, 256, 0, stream>>>(H, O, T);
    k_bin<<<ABLK, 256, 0, stream>>>(row, col, O, T, staging);
    k_csr<<<NREG, 512, 0, stream>>>(staging, T, offs, dinv, epack, x, bufB);

    // fused layers: hs_next = fp16(dinv (.) relu((A_hat-sum of hs) @ W + b))
    k_fused<<<nblk_F, 512, 0, stream>>>(offs, epack, dinv, bufB, W1, b1, bufA,
                                        nullptr, nullptr);
    k_fused<<<nblk_F, 512, 0, stream>>>(offs, epack, dinv, bufA, W2, b2, bufB,
                                        nullptr, nullptr);
    // layer 3: no h write; outputs pooled directly (pool zeroed by k_hist)
    k_fused<<<nblk_F, 512, 0, stream>>>(offs, epack, dinv, bufB, W3, b3, nullptr,
                                        batch, pool);

    k_div<<<(N_GRAPHS * DF + 255) / 256, 256, 0, stream>>>(pool, batch, out);
}